// Round 13
// baseline (594.572 us; speedup 1.0000x reference)
//
#include <hip/hip_runtime.h>
#include <hip/hip_bf16.h>
#include <stdint.h>

#define XS 128
#define YS 128
#define ZS 8
#define NQ (XS*YS*ZS)        // 131072 queries
#define CDIM 128
#define NH 8
#define HD 16
#define DH 192
#define DW 640
#define NPIX (DH*DW)
#define NVPIX 10080          // 7680 + 1920 + 480

typedef float f32x4 __attribute__((ext_vector_type(4)));
typedef short s16x8 __attribute__((ext_vector_type(8)));

__device__ __forceinline__ float b2f(unsigned short u){
    union { unsigned int i; float f; } v; v.i = ((unsigned int)u) << 16; return v.f;
}
__device__ __forceinline__ unsigned short f2b(float f){
    __hip_bfloat16 h = __float2bfloat16(f);
    return *reinterpret_cast<unsigned short*>(&h);
}
__device__ __forceinline__ float blo(unsigned int u){
    union { unsigned int i; float f; } v; v.i = u << 16; return v.f;
}
__device__ __forceinline__ float bhi(unsigned int u){
    union { unsigned int i; float f; } v; v.i = u & 0xffff0000u; return v.f;
}

// ====== fused prep: Wbf build | value GEMM | mask (fp64 inverse in-block) ======
__global__ __launch_bounds__(256)
void prep_kernel(int nW, int nVal,
                 const float* __restrict__ Woff,
                 const float* __restrict__ Wattw,
                 const float* __restrict__ Wout,
                 unsigned short* __restrict__ Wbf,
                 const float* __restrict__ f0,
                 const float* __restrict__ f1,
                 const float* __restrict__ f2,
                 const float* __restrict__ Wv,
                 const float* __restrict__ bv,
                 unsigned short* __restrict__ value,  // [NH][NVPIX][HD]
                 const float* __restrict__ depth,
                 const float* __restrict__ K,
                 const float* __restrict__ E,
                 const float* __restrict__ vorigin,
                 unsigned char* __restrict__ mask){
    __shared__ __align__(16) unsigned char smem[16384];
    const int t = threadIdx.x;

    if ((int)blockIdx.x < nW){
        int idx = blockIdx.x*256 + t;
        if (idx < 24576)      Wbf[idx] = f2b(Woff[idx]);
        else if (idx < 36864) Wbf[idx] = f2b(Wattw[idx-24576]);
        else if (idx < 40960) Wbf[idx] = 0;
        else if (idx < 57344) Wbf[idx] = f2b(Wout[idx-40960]);
    } else if ((int)blockIdx.x < nW + nVal){
        // ---------- value: 8 pixels per block (two 128-thread halves) ----------
        const int half = t >> 7, tt = t & 127;
        const int p0 = (blockIdx.x - nW)*8 + half*4;
        float (*fl)[4] = (float(*)[4])(smem + half*2048);
        const float* src; int hw, lp;
        if (p0 < 7680)      { src=f0; hw=7680; lp=p0; }
        else if (p0 < 9600) { src=f1; hw=1920; lp=p0-7680; }
        else                { src=f2; hw=480;  lp=p0-9600; }
        float4 v = *(const float4*)(src + tt*hw + lp);
        fl[tt][0]=v.x; fl[tt][1]=v.y; fl[tt][2]=v.z; fl[tt][3]=v.w;
        __syncthreads();
        float bb = bv[tt];
        float acc[4] = {bb,bb,bb,bb};
        const float4* wrow = (const float4*)(Wv + tt*CDIM);
        #pragma unroll 8
        for (int kc=0; kc<32; ++kc){
            float4 w = wrow[kc];
            #pragma unroll
            for (int u=0;u<4;u++){
                float wu = (u==0)?w.x:(u==1)?w.y:(u==2)?w.z:w.w;
                float4 fv = *(const float4*)fl[kc*4+u];
                acc[0] += fv.x*wu; acc[1] += fv.y*wu; acc[2] += fv.z*wu; acc[3] += fv.w*wu;
            }
        }
        const int hh = tt >> 4, cc = tt & 15;
        #pragma unroll
        for (int i=0;i<4;i++)
            value[((size_t)hh*NVPIX + (size_t)(p0+i))*HD + cc] = f2b(acc[i]);
    } else {
        // ---------- mask: fp64 K/E inverse computed per block, LDS broadcast ----------
        double* invs = (double*)smem;    // [21]
        if (t == 0){
            double k[3][3], e[4][4];
            for (int i=0;i<9;i++)  k[i/3][i%3] = (double)K[i];
            for (int i=0;i<16;i++) e[i/4][i%4] = (double)E[i];
            double det = k[0][0]*(k[1][1]*k[2][2]-k[1][2]*k[2][1])
                       - k[0][1]*(k[1][0]*k[2][2]-k[1][2]*k[2][0])
                       + k[0][2]*(k[1][0]*k[2][1]-k[1][1]*k[2][0]);
            double id = 1.0/det;
            invs[0]=(k[1][1]*k[2][2]-k[1][2]*k[2][1])*id;
            invs[1]=(k[0][2]*k[2][1]-k[0][1]*k[2][2])*id;
            invs[2]=(k[0][1]*k[1][2]-k[0][2]*k[1][1])*id;
            invs[3]=(k[1][2]*k[2][0]-k[1][0]*k[2][2])*id;
            invs[4]=(k[0][0]*k[2][2]-k[0][2]*k[2][0])*id;
            invs[5]=(k[0][2]*k[1][0]-k[0][0]*k[1][2])*id;
            invs[6]=(k[1][0]*k[2][1]-k[1][1]*k[2][0])*id;
            invs[7]=(k[0][1]*k[2][0]-k[0][0]*k[2][1])*id;
            invs[8]=(k[0][0]*k[1][1]-k[0][1]*k[1][0])*id;
            double a[4][8];
            for (int i=0;i<4;i++){ for(int j=0;j<4;j++){ a[i][j]=e[i][j]; a[i][4+j]=(i==j)?1.0:0.0; } }
            for (int c=0;c<4;c++){
                int piv=c; double best=fabs(a[c][c]);
                for (int r=c+1;r<4;r++){ double v=fabs(a[r][c]); if (v>best){best=v;piv=r;} }
                if (piv!=c){ for (int j=0;j<8;j++){ double tmp=a[c][j]; a[c][j]=a[piv][j]; a[piv][j]=tmp; } }
                double pv = 1.0/a[c][c];
                for (int j=0;j<8;j++) a[c][j]*=pv;
                for (int r=0;r<4;r++){
                    if (r==c) continue;
                    double f=a[r][c];
                    for(int j=0;j<8;j++) a[r][j]-=f*a[c][j];
                }
            }
            for (int i=0;i<12;i++) invs[9+i] = a[i/4][4 + (i%4)];
        }
        __syncthreads();
        int tid = ((int)blockIdx.x - nW - nVal)*256 + t;
        if (tid >= NPIX) return;
        int gx = tid % DW, gy = tid / DW;
        double d  = (double)depth[tid];
        double X0 = (double)gx * d, X1 = (double)gy * d, X2 = d;
        double c0 = invs[0]*X0 + invs[1]*X1 + invs[2]*X2;
        double c1 = invs[3]*X0 + invs[4]*X1 + invs[5]*X2;
        double c2 = invs[6]*X0 + invs[7]*X1 + invs[8]*X2;
        const double* iE = invs + 9;
        double w0 = iE[0]*c0 + iE[1]*c1 + iE[2]*c2  + iE[3];
        double w1 = iE[4]*c0 + iE[5]*c1 + iE[6]*c2  + iE[7];
        double w2 = iE[8]*c0 + iE[9]*c1 + iE[10]*c2 + iE[11];
        double v0 = (w0-(double)vorigin[0])/0.4 - 0.5;
        double v1 = (w1-(double)vorigin[1])/0.4 - 0.5;
        double v2 = ((w2-(double)vorigin[2])/0.4 - 0.5) / 2.0;
        int xi = (int)v0, yi = (int)v1, zi = (int)v2;
        if (xi>=0 && xi<XS && yi>=0 && yi<YS && zi>=0 && zi<ZS)
            mask[(xi*YS + yi)*ZS + zi] = 1;
    }
}

// ======== attn_fused16: 16 queries/block for 6 blocks/CU occupancy ========
// LDS map (27024 B total, <= 27306 for 6 blocks/CU):
//   0      Ob[2][288][8] u16                      (9216)
//   9216   region: qbf[16][256]B swz (4096, ph0-1) / desc[768]x16B (12288, per sub-round)
//                  / out2[8][128] f32 (4096)      (12288)
//   21504  obf[16][128] bf16 swz                  (4096)
//   25600  bias[288] f32                          (1152)
//   26752  rp_s[32] f32                           (128)
//   26880  mask_s[16]                             (16, padded)
//   26896  wredp[2][4][4] f32                     (128)
__global__ __launch_bounds__(256, 6)
void attn_fused(const float* __restrict__ q_in,
                const float* __restrict__ refpix,
                const unsigned short* __restrict__ Wbf,    // [320][128] bf16 (padded)
                const float* __restrict__ boff,
                const float* __restrict__ battw,
                const unsigned short* __restrict__ value,  // [NH][NVPIX][HD]
                const unsigned short* __restrict__ WoutBf, // [128][128] bf16
                const float* __restrict__ bout,
                const float* __restrict__ lng,
                const float* __restrict__ lnb,
                const unsigned char* __restrict__ mask,
                float* __restrict__ dout){
    const int nq0 = blockIdx.x * 16;
    const int t = threadIdx.x;
    __shared__ __align__(16) unsigned char smem[27024];
    unsigned short* Ob    = (unsigned short*)smem;
    unsigned char*  qbfB  = smem + 9216;
    unsigned char*  descB = smem + 9216;
    float*          out2  = (float*)(smem + 9216);
    unsigned char*  obfB  = smem + 21504;
    float*          bias  = (float*)(smem + 25600);
    float*          rp_s  = (float*)(smem + 26752);
    unsigned char*  mask_s= smem + 26880;
    float*          wredp = (float*)(smem + 26896);

    // ---- stage: q -> swizzled bf16, bias, rp, mask, zero obf pad rows ----
    #pragma unroll
    for (int i=0;i<2;i++){
        int idx = t + i*256;              // 512 float4s = 16 rows x 32
        int row = idx >> 5, c4 = idx & 31;
        float4 qv = ((const float4*)(q_in + (size_t)(nq0+row)*CDIM))[c4];
        unsigned int pk0 = (unsigned int)f2b(qv.x) | ((unsigned int)f2b(qv.y)<<16);
        unsigned int pk1 = (unsigned int)f2b(qv.z) | ((unsigned int)f2b(qv.w)<<16);
        unsigned int bo = ((unsigned int)(row*256 + c4*8)) ^ (unsigned int)((row&7)<<4);
        *(unsigned int*)(qbfB + bo)     = pk0;
        *(unsigned int*)(qbfB + bo + 4) = pk1;
    }
    for (int i=t;i<288;i+=256) bias[i] = (i<192)? boff[i] : battw[i-192];
    ((unsigned int*)obfB)[512 + t] = 0;   // zero obf rows 8..15
    ((unsigned int*)obfB)[768 + t] = 0;
    if (t < 32) rp_s[t] = refpix[nq0*2 + t];
    if (t < 16) mask_s[t] = mask[nq0 + t];
    __syncthreads();

    // ---- offaw MFMA: 5 feature tiles x 1 query tile x 4 K-steps per wave ----
    {
        const int w = t >> 6, lane = t & 63, lr = lane & 15, lg = lane >> 4;
        const int nt0 = w*5;
        f32x4 acc[5];
        #pragma unroll
        for (int j=0;j<5;j++) acc[j]=(f32x4){0,0,0,0};
        #pragma unroll
        for (int ks=0; ks<4; ++ks){
            unsigned int bo = ((unsigned int)(lr*256 + ks*64 + lg*16)) ^ (unsigned int)((lr&7)<<4);
            s16x8 bfrag = *(const s16x8*)(qbfB + bo);
            const unsigned short* wp = Wbf + (size_t)(nt0*16 + lr)*CDIM + ks*32 + lg*8;
            #pragma unroll
            for (int j=0;j<5;++j){
                s16x8 af = *(const s16x8*)(wp + j*16*CDIM);
                acc[j] = __builtin_amdgcn_mfma_f32_16x16x32_bf16(af, bfrag, acc[j], 0, 0, 0);
            }
        }
        #pragma unroll
        for (int j=0;j<5;++j){
            int nt = nt0 + j;
            if (nt < 18){
                int base = (lr>>3)*2304 + (lr&7);
                #pragma unroll
                for (int r=0;r<4;++r){
                    int f = nt*16 + lg*4 + r;
                    Ob[base + f*8] = f2b(acc[j][r] + bias[f]);
                }
            }
        }
    }
    __syncthreads();

    // ---- softmax: 16q x 8h = 128 tasks ----
    if (t < 128){
        int q = t >> 3, h = t & 7;
        unsigned short* p = Ob + (q>>3)*2304 + (192 + h*12)*8 + (q&7);
        float e[12]; float m = -1e30f;
        #pragma unroll
        for (int i=0;i<12;i++){ e[i] = b2f(p[i*8]); m = fmaxf(m, e[i]); }
        float s = 0.f;
        #pragma unroll
        for (int i=0;i<12;i++){ e[i] = __expf(e[i]-m); s += e[i]; }
        float is = 1.f/s;
        #pragma unroll
        for (int i=0;i<12;i++) p[i*8] = f2b(e[i]*is);
    }
    __syncthreads();

    // ---- 2 sub-rounds of 8 queries ----
    for (int sr = 0; sr < 2; ++sr){
        const unsigned short* raw = Ob + sr*2304;
        const int nsr = nq0 + sr*8;

        // desc: 768 sample descriptors
        for (int idx = t; idx < 768; idx += 256){
            int q = idx & 7, hp = idx >> 3;
            int lp = hp % 12;
            float fw, fh; int Wl, Hl, st;
            if (lp < 4)      { fw=160.f; fh=48.f; Wl=160; Hl=48; st=0; }
            else if (lp < 8) { fw=80.f;  fh=24.f; Wl=80;  Hl=24; st=7680; }
            else             { fw=40.f;  fh=12.f; Wl=40;  Hl=12; st=9600; }
            float offx = b2f(raw[(hp*2)*8 + q]);
            float offy = b2f(raw[(hp*2+1)*8 + q]);
            float aw   = b2f(raw[(192+hp)*8 + q]);
            float x = rp_s[(sr*8+q)*2+0]*fw - 0.5f + offx;
            float y = rp_s[(sr*8+q)*2+1]*fh - 0.5f + offy;
            float x0f = floorf(x), y0f = floorf(y);
            float lx = x-x0f, ly = y-y0f;
            int x0 = (int)x0f, y0 = (int)y0f;
            bool x0ok = (x0>=0)&&(x0<Wl), x1ok=(x0+1>=0)&&(x0+1<Wl);
            bool y0ok = (y0>=0)&&(y0<Hl), y1ok=(y0+1>=0)&&(y0+1<Hl);
            float w00 = (x0ok&&y0ok)? (1.f-lx)*(1.f-ly)*aw : 0.f;
            float w01 = (x1ok&&y0ok)? lx*(1.f-ly)*aw       : 0.f;
            float w10 = (x0ok&&y1ok)? (1.f-lx)*ly*aw       : 0.f;
            float w11 = (x1ok&&y1ok)? lx*ly*aw             : 0.f;
            int yc0 = min(max(y0,0),Hl-1), yc1 = min(max(y0+1,0),Hl-1);
            int xc0 = min(max(x0,0),Wl-1), xc1 = min(max(x0+1,0),Wl-1);
            unsigned int rb0 = (unsigned int)(st + yc0*Wl), rb1 = (unsigned int)(st + yc1*Wl);
            uint4 d;
            d.x = (rb0+(unsigned int)xc0) | ((rb0+(unsigned int)xc1)<<16);
            d.y = (rb1+(unsigned int)xc0) | ((rb1+(unsigned int)xc1)<<16);
            d.z = (unsigned int)f2b(w00) | ((unsigned int)f2b(w01)<<16);
            d.w = (unsigned int)f2b(w10) | ((unsigned int)f2b(w11)<<16);
            *(uint4*)(descB + (((unsigned int)(idx ^ ((idx>>5)&7)))<<4)) = d;
        }
        __syncthreads();

        // qv prefetch: issue residual q loads now (hidden under sampling)
        float qv[4];
        {
            const int r = t & 127, qb = t >> 7;
            #pragma unroll
            for (int qi4=0;qi4<4;qi4++)
                qv[qi4] = q_in[(size_t)(nsr + qb*4 + qi4)*CDIM + r];
        }

        // sampling: 2 channels x 2 queries per thread, u32-offset dword gathers
        {
            const int cp = t & 7, hs = (t>>3) & 7, qgs = t >> 6;
            const unsigned int vbase = (unsigned int)hs*(NVPIX*HD*2) + (unsigned int)cp*4;
            const char* vb = (const char*)value;
            float av0x=0.f, av0y=0.f, av1x=0.f, av1y=0.f;
            #pragma unroll
            for (int lp=0; lp<12; ++lp){
                #pragma unroll
                for (int qi2=0; qi2<2; ++qi2){
                    int idx = (hs*12+lp)*8 + qgs*2 + qi2;
                    uint4 d = *(const uint4*)(descB + (((unsigned int)(idx ^ ((idx>>5)&7)))<<4));
                    unsigned int o00 = vbase + ((d.x & 0xffffu)<<5);
                    unsigned int o01 = vbase + ((d.x >> 16)<<5);
                    unsigned int o10 = vbase + ((d.y & 0xffffu)<<5);
                    unsigned int o11 = vbase + ((d.y >> 16)<<5);
                    unsigned int u00 = *(const unsigned int*)(vb + o00);
                    unsigned int u01 = *(const unsigned int*)(vb + o01);
                    unsigned int u10 = *(const unsigned int*)(vb + o10);
                    unsigned int u11 = *(const unsigned int*)(vb + o11);
                    float w00 = blo(d.z), w01 = bhi(d.z), w10 = blo(d.w), w11 = bhi(d.w);
                    float sx = blo(u00)*w00 + blo(u01)*w01 + blo(u10)*w10 + blo(u11)*w11;
                    float sy = bhi(u00)*w00 + bhi(u01)*w01 + bhi(u10)*w10 + bhi(u11)*w11;
                    if (qi2 == 0){ av0x += sx; av0y += sy; }
                    else         { av1x += sx; av1y += sy; }
                }
            }
            const int q0q = qgs*2;
            unsigned int pk0 = (unsigned int)f2b(av0x) | ((unsigned int)f2b(av0y)<<16);
            unsigned int pk1 = (unsigned int)f2b(av1x) | ((unsigned int)f2b(av1y)<<16);
            unsigned int bo0 = (unsigned int)(q0q*256 + hs*32 + cp*4)     ^ (unsigned int)((q0q&7)<<4);
            unsigned int bo1 = (unsigned int)((q0q+1)*256 + hs*32 + cp*4) ^ (unsigned int)(((q0q+1)&7)<<4);
            *(unsigned int*)(obfB + bo0) = pk0;
            *(unsigned int*)(obfB + bo1) = pk1;
        }
        __syncthreads();

        // Wout projection via MFMA, bout folded
        {
            const int w = t >> 6, lane = t & 63, lr = lane & 15, lg = lane >> 4;
            f32x4 a0 = (f32x4){0.f,0.f,0.f,0.f};
            f32x4 a1 = (f32x4){0.f,0.f,0.f,0.f};
            #pragma unroll
            for (int ks=0; ks<4; ++ks){
                unsigned int bo = (unsigned int)(lr*256 + ks*64 + lg*16) ^ (unsigned int)((lr&7)<<4);
                s16x8 bfrag = *(const s16x8*)(obfB + bo);
                const unsigned short* wp = WoutBf + (size_t)(w*32 + lr)*CDIM + ks*32 + lg*8;
                s16x8 af0 = *(const s16x8*)(wp);
                s16x8 af1 = *(const s16x8*)(wp + 16*CDIM);
                a0 = __builtin_amdgcn_mfma_f32_16x16x32_bf16(af0, bfrag, a0, 0, 0, 0);
                a1 = __builtin_amdgcn_mfma_f32_16x16x32_bf16(af1, bfrag, a1, 0, 0, 0);
            }
            if (lr < 8){
                int f0 = w*32 + lg*4;
                float4 b0 = *(const float4*)(bout + f0);
                float4 b1 = *(const float4*)(bout + f0 + 16);
                float4 v0, v1;
                v0.x = a0[0]+b0.x; v0.y = a0[1]+b0.y; v0.z = a0[2]+b0.z; v0.w = a0[3]+b0.w;
                v1.x = a1[0]+b1.x; v1.y = a1[1]+b1.y; v1.z = a1[2]+b1.z; v1.w = a1[3]+b1.w;
                *(float4*)(out2 + lr*CDIM + f0)      = v0;
                *(float4*)(out2 + lr*CDIM + f0 + 16) = v1;
            }
        }
        __syncthreads();

        // residual (prefetched qv) + single-pass LN + mask + store
        {
            const int r = t & 127;
            const int qb = t >> 7;
            const int wv = t >> 6;
            float hv[4], s1[4], s2[4];
            #pragma unroll
            for (int qi4=0;qi4<4;qi4++){
                hv[qi4] = qv[qi4] + out2[(qb*4+qi4)*CDIM + r];
                s1[qi4] = hv[qi4];
                s2[qi4] = hv[qi4]*hv[qi4];
            }
            #pragma unroll
            for (int off=32; off>0; off>>=1){
                #pragma unroll
                for (int qi4=0;qi4<4;qi4++){
                    s1[qi4] += __shfl_xor(s1[qi4], off, 64);
                    s2[qi4] += __shfl_xor(s2[qi4], off, 64);
                }
            }
            if ((t&63)==0){
                #pragma unroll
                for (int qi4=0;qi4<4;qi4++){
                    wredp[0*16 + wv*4 + qi4] = s1[qi4];
                    wredp[1*16 + wv*4 + qi4] = s2[qi4];
                }
            }
            __syncthreads();

            float res[4];
            const float g = lng[r], b = lnb[r];
            #pragma unroll
            for (int qi4=0;qi4<4;qi4++){
                float mu  = (wredp[0*16 + (qb*2)*4 + qi4] + wredp[0*16 + (qb*2+1)*4 + qi4]) * (1.f/128.f);
                float msq = (wredp[1*16 + (qb*2)*4 + qi4] + wredp[1*16 + (qb*2+1)*4 + qi4]) * (1.f/128.f);
                float var = msq - mu*mu;
                float nv  = (hv[qi4]-mu) * __frsqrt_rn(var + 1e-5f) * g + b;
                res[qi4] = mask_s[sr*8 + qb*4+qi4] ? nv : qv[qi4];
            }
            float4 o; o.x=res[0]; o.y=res[1]; o.z=res[2]; o.w=res[3];
            *(float4*)(dout + (size_t)r*NQ + nsr + qb*4) = o;
        }
        __syncthreads();   // out2/desc region + wredp safe for next sub-round
    }
}

extern "C" void kernel_launch(void* const* d_in, const int* in_sizes, int n_in,
                              void* d_out, int out_size, void* d_ws, size_t ws_size,
                              hipStream_t stream){
    const float* scene  = (const float*)d_in[0];
    const float* f0     = (const float*)d_in[1];
    const float* f1     = (const float*)d_in[2];
    const float* f2     = (const float*)d_in[3];
    const float* depth  = (const float*)d_in[4];
    const float* K      = (const float*)d_in[5];
    const float* E      = (const float*)d_in[6];
    const float* vorig  = (const float*)d_in[7];
    const float* refpix = (const float*)d_in[8];
    const float* Wv     = (const float*)d_in[9];
    const float* bv     = (const float*)d_in[10];
    const float* Woff   = (const float*)d_in[11];
    const float* boff   = (const float*)d_in[12];
    const float* Wattw  = (const float*)d_in[13];
    const float* battw  = (const float*)d_in[14];
    const float* Wout   = (const float*)d_in[15];
    const float* bout   = (const float*)d_in[16];
    const float* lng    = (const float*)d_in[17];
    const float* lnb    = (const float*)d_in[18];

    char* ws = (char*)d_ws;
    // mask(131072) + value(2580480) + Wbf(114688)
    unsigned char*  mask   = (unsigned char*)(ws + 512);
    unsigned short* value  = (unsigned short*)(ws + 512 + 131072);
    unsigned short* Wbf    = (unsigned short*)(ws + 512 + 131072 + 2580480);
    unsigned short* WoutBf = Wbf + 40960;

    hipMemsetAsync(mask, 0, NQ, stream);

    int nW    = 57344/256;          // 224
    int nVal  = NVPIX/8;            // 1260
    int nMask = (NPIX+255)/256;     // 480
    prep_kernel<<<nW + nVal + nMask, 256, 0, stream>>>(
        nW, nVal, Woff, Wattw, Wout, Wbf,
        f0, f1, f2, Wv, bv, value,
        depth, K, E, vorig, mask);
    attn_fused<<<NQ/16, 256, 0, stream>>>(scene, refpix, Wbf, boff, battw, value,
                                          WoutBf, bout, lng, lnb, mask,
                                          (float*)d_out);
}

// Round 14
// 444.953 us; speedup vs baseline: 1.3363x; 1.3363x over previous
//
#include <hip/hip_runtime.h>
#include <hip/hip_bf16.h>
#include <stdint.h>

#define XS 128
#define YS 128
#define ZS 8
#define NQ (XS*YS*ZS)        // 131072 queries
#define CDIM 128
#define NH 8
#define HD 16
#define DH 192
#define DW 640
#define NPIX (DH*DW)
#define NVPIX 10080          // 7680 + 1920 + 480

typedef float f32x4 __attribute__((ext_vector_type(4)));
typedef short s16x8 __attribute__((ext_vector_type(8)));

__device__ __forceinline__ float b2f(unsigned short u){
    union { unsigned int i; float f; } v; v.i = ((unsigned int)u) << 16; return v.f;
}
__device__ __forceinline__ unsigned short f2b(float f){
    __hip_bfloat16 h = __float2bfloat16(f);
    return *reinterpret_cast<unsigned short*>(&h);
}
__device__ __forceinline__ float blo(unsigned int u){
    union { unsigned int i; float f; } v; v.i = u << 16; return v.f;
}
__device__ __forceinline__ float bhi(unsigned int u){
    union { unsigned int i; float f; } v; v.i = u & 0xffff0000u; return v.f;
}

// ------------- inverse of K/E (1 thread) + weight prep -------------
// Wbf: [0,24576) Woff | [24576,36864) Wattw | [36864,40960) zero pad | [40960,57344) Wout
// WvT (f32): WvT[ci*128+co] = Wv[co*128+ci]
__global__ __launch_bounds__(256)
void inv_kernel(const float* __restrict__ K,
                const float* __restrict__ E,
                double* __restrict__ inv_out,
                const float* __restrict__ Woff,
                const float* __restrict__ Wattw,
                const float* __restrict__ Wout,
                const float* __restrict__ Wv,
                unsigned short* __restrict__ Wbf,
                float* __restrict__ WvT){
    if (blockIdx.x != 0){
        int idx = (blockIdx.x-1)*256 + threadIdx.x;
        if (idx < 24576)      Wbf[idx] = f2b(Woff[idx]);
        else if (idx < 36864) Wbf[idx] = f2b(Wattw[idx-24576]);
        else if (idx < 40960) Wbf[idx] = 0;
        else if (idx < 57344) Wbf[idx] = f2b(Wout[idx-40960]);
        else if (idx < 73728){
            int j = idx - 57344;
            int ci = j >> 7, co = j & 127;
            WvT[j] = Wv[co*128 + ci];
        }
        return;
    }
    if (threadIdx.x != 0) return;
    double k[3][3], e[4][4];
    for (int i=0;i<9;i++)  k[i/3][i%3] = (double)K[i];
    for (int i=0;i<16;i++) e[i/4][i%4] = (double)E[i];
    double det = k[0][0]*(k[1][1]*k[2][2]-k[1][2]*k[2][1])
               - k[0][1]*(k[1][0]*k[2][2]-k[1][2]*k[2][0])
               + k[0][2]*(k[1][0]*k[2][1]-k[1][1]*k[2][0]);
    double id = 1.0/det;
    double inv[3][3];
    inv[0][0]=(k[1][1]*k[2][2]-k[1][2]*k[2][1])*id;
    inv[0][1]=(k[0][2]*k[2][1]-k[0][1]*k[2][2])*id;
    inv[0][2]=(k[0][1]*k[1][2]-k[0][2]*k[1][1])*id;
    inv[1][0]=(k[1][2]*k[2][0]-k[1][0]*k[2][2])*id;
    inv[1][1]=(k[0][0]*k[2][2]-k[0][2]*k[2][0])*id;
    inv[1][2]=(k[0][2]*k[1][0]-k[0][0]*k[1][2])*id;
    inv[2][0]=(k[1][0]*k[2][1]-k[1][1]*k[2][0])*id;
    inv[2][1]=(k[0][1]*k[2][0]-k[0][0]*k[2][1])*id;
    inv[2][2]=(k[0][0]*k[1][1]-k[0][1]*k[1][0])*id;
    for (int i=0;i<9;i++) inv_out[i] = inv[i/3][i%3];
    double a[4][8];
    for (int i=0;i<4;i++){ for(int j=0;j<4;j++){ a[i][j]=e[i][j]; a[i][4+j]=(i==j)?1.0:0.0; } }
    for (int c=0;c<4;c++){
        int piv=c; double best=fabs(a[c][c]);
        for (int r=c+1;r<4;r++){ double v=fabs(a[r][c]); if (v>best){best=v;piv=r;} }
        if (piv!=c){ for (int j=0;j<8;j++){ double tmp=a[c][j]; a[c][j]=a[piv][j]; a[piv][j]=tmp; } }
        double pv = 1.0/a[c][c];
        for (int j=0;j<8;j++) a[c][j]*=pv;
        for (int r=0;r<4;r++){
            if (r==c) continue;
            double f=a[r][c];
            for(int j=0;j<8;j++) a[r][j]-=f*a[c][j];
        }
    }
    for (int i=0;i<16;i++) inv_out[9+i] = a[i/4][4 + (i%4)];
}

// ================= prep2: value GEMM (WvT-coalesced) | mask =================
__global__ __launch_bounds__(256)
void prep2_kernel(int nVal,
                  const float* __restrict__ f0,
                  const float* __restrict__ f1,
                  const float* __restrict__ f2,
                  const float* __restrict__ WvT,   // [128 ci][128 co] f32
                  const float* __restrict__ bv,
                  unsigned short* __restrict__ value,  // [NH][NVPIX][HD]
                  const float* __restrict__ depth,
                  const double* __restrict__ invm,
                  const float* __restrict__ vorigin,
                  unsigned char* __restrict__ mask){
    __shared__ float fl[128][8];     // [ci][pix]
    const int t = threadIdx.x;
    if ((int)blockIdx.x < nVal){
        const int p0 = blockIdx.x*8;
        const float* src; int hw, lp;
        if (p0 < 7680)      { src=f0; hw=7680; lp=p0; }
        else if (p0 < 9600) { src=f1; hw=1920; lp=p0-7680; }
        else                { src=f2; hw=480;  lp=p0-9600; }
        {
            int ch = t >> 1, po = (t & 1)*4;
            float4 v = *(const float4*)(src + (size_t)ch*hw + lp + po);
            fl[ch][po+0]=v.x; fl[ch][po+1]=v.y; fl[ch][po+2]=v.z; fl[ch][po+3]=v.w;
        }
        __syncthreads();
        const int pix = t >> 5, cq = t & 31;      // co = cq*4 .. cq*4+3
        float4 bvv = *(const float4*)(bv + cq*4);
        float acc0=bvv.x, acc1=bvv.y, acc2=bvv.z, acc3=bvv.w;
        const float4* wvt = (const float4*)WvT + cq;
        #pragma unroll 4
        for (int ci=0; ci<128; ++ci){
            float4 w4 = wvt[ci*32];
            float fv = fl[ci][pix];
            acc0 += w4.x*fv; acc1 += w4.y*fv; acc2 += w4.z*fv; acc3 += w4.w*fv;
        }
        const int h = cq >> 2, cc0 = (cq & 3)*4;
        unsigned short* vp = value + ((size_t)h*NVPIX + (size_t)(p0+pix))*HD + cc0;
        ushort4 o; o.x=f2b(acc0); o.y=f2b(acc1); o.z=f2b(acc2); o.w=f2b(acc3);
        *(ushort4*)vp = o;
    } else {
        int tid = (blockIdx.x - nVal)*256 + t;
        if (tid >= NPIX) return;
        int gx = tid % DW, gy = tid / DW;
        double d  = (double)depth[tid];
        double X0 = (double)gx * d, X1 = (double)gy * d, X2 = d;
        double c0 = invm[0]*X0 + invm[1]*X1 + invm[2]*X2;
        double c1 = invm[3]*X0 + invm[4]*X1 + invm[5]*X2;
        double c2 = invm[6]*X0 + invm[7]*X1 + invm[8]*X2;
        const double* iE = invm + 9;
        double w0 = iE[0]*c0 + iE[1]*c1 + iE[2]*c2  + iE[3];
        double w1 = iE[4]*c0 + iE[5]*c1 + iE[6]*c2  + iE[7];
        double w2 = iE[8]*c0 + iE[9]*c1 + iE[10]*c2 + iE[11];
        double v0 = (w0-(double)vorigin[0])/0.4 - 0.5;
        double v1 = (w1-(double)vorigin[1])/0.4 - 0.5;
        double v2 = ((w2-(double)vorigin[2])/0.4 - 0.5) / 2.0;
        int xi = (int)v0, yi = (int)v1, zi = (int)v2;
        if (xi>=0 && xi<XS && yi>=0 && yi<YS && zi>=0 && zi<ZS)
            mask[(xi*YS + yi)*ZS + zi] = 1;
    }
}

// ======== attn_fused32: offaw MFMA + softmax + 4x{desc, qv-prefetch, sampling, Wout, LN} ========
__global__ __launch_bounds__(256, 2)
void attn_fused(const float* __restrict__ q_in,
                const float* __restrict__ refpix,
                const unsigned short* __restrict__ Wbf,    // [320][128] bf16 (padded)
                const float* __restrict__ boff,
                const float* __restrict__ battw,
                const unsigned short* __restrict__ value,  // [NH][NVPIX][HD]
                const unsigned short* __restrict__ WoutBf, // [128][128] bf16
                const float* __restrict__ bout,
                const float* __restrict__ lng,
                const float* __restrict__ lnb,
                const unsigned char* __restrict__ mask,
                float* __restrict__ dout){
    const int nq0 = blockIdx.x * 32;
    const int t = threadIdx.x;
    __shared__ __align__(16) unsigned char smem[36384];
    unsigned short* Ob    = (unsigned short*)smem;
    unsigned char*  qbfB  = smem + 18432;
    unsigned char*  descB = smem + 18432;
    float*          out2  = (float*)(smem + 18432);
    unsigned char*  obfB  = smem + 30720;
    float*          bias  = (float*)(smem + 34816);
    float*          rp_s  = (float*)(smem + 35968);
    unsigned char*  mask_s= smem + 36224;
    float*          wredp = (float*)(smem + 36256);

    // ---- stage: q -> swizzled bf16, bias, rp, mask, zero obf pad rows ----
    #pragma unroll
    for (int i=0;i<4;i++){
        int idx = t + i*256;              // 1024 float4s = 32 rows x 32
        int row = idx >> 5, c4 = idx & 31;
        float4 qv = ((const float4*)(q_in + (size_t)(nq0+row)*CDIM))[c4];
        unsigned int pk0 = (unsigned int)f2b(qv.x) | ((unsigned int)f2b(qv.y)<<16);
        unsigned int pk1 = (unsigned int)f2b(qv.z) | ((unsigned int)f2b(qv.w)<<16);
        unsigned int bo = ((unsigned int)(row*256 + c4*8)) ^ (unsigned int)((row&7)<<4);
        *(unsigned int*)(qbfB + bo)     = pk0;
        *(unsigned int*)(qbfB + bo + 4) = pk1;
    }
    for (int i=t;i<288;i+=256) bias[i] = (i<192)? boff[i] : battw[i-192];
    ((unsigned int*)obfB)[512 + t] = 0;   // zero obf rows 8..15
    ((unsigned int*)obfB)[768 + t] = 0;
    if (t < 64) rp_s[t] = refpix[nq0*2 + t];
    if (t < 32) mask_s[t] = mask[nq0 + t];
    __syncthreads();

    // ---- offaw MFMA: 5 feature tiles x 2 query tiles x 4 K-steps per wave ----
    {
        const int w = t >> 6, lane = t & 63, lr = lane & 15, lg = lane >> 4;
        const int nt0 = w*5;
        f32x4 acc[5][2];
        #pragma unroll
        for (int j=0;j<5;j++){ acc[j][0]=(f32x4){0,0,0,0}; acc[j][1]=(f32x4){0,0,0,0}; }
        #pragma unroll
        for (int ks=0; ks<4; ++ks){
            s16x8 bf[2];
            #pragma unroll
            for (int qt=0;qt<2;qt++){
                int qrow = qt*16 + lr;
                unsigned int bo = ((unsigned int)(qrow*256 + ks*64 + lg*16)) ^ (unsigned int)((qrow&7)<<4);
                bf[qt] = *(const s16x8*)(qbfB + bo);
            }
            const unsigned short* wp = Wbf + (size_t)(nt0*16 + lr)*CDIM + ks*32 + lg*8;
            #pragma unroll
            for (int j=0;j<5;++j){
                s16x8 af = *(const s16x8*)(wp + j*16*CDIM);
                acc[j][0] = __builtin_amdgcn_mfma_f32_16x16x32_bf16(af, bf[0], acc[j][0], 0, 0, 0);
                acc[j][1] = __builtin_amdgcn_mfma_f32_16x16x32_bf16(af, bf[1], acc[j][1], 0, 0, 0);
            }
        }
        #pragma unroll
        for (int j=0;j<5;++j){
            int nt = nt0 + j;
            if (nt < 18){
                #pragma unroll
                for (int qt=0;qt<2;qt++){
                    int q = qt*16 + lr;
                    int base = (q>>3)*2304 + (q&7);
                    #pragma unroll
                    for (int r=0;r<4;++r){
                        int f = nt*16 + lg*4 + r;
                        Ob[base + f*8] = f2b(acc[j][qt][r] + bias[f]);
                    }
                }
            }
        }
    }
    __syncthreads();

    // ---- softmax: 32q x 8h = 256 tasks, one per thread ----
    {
        int q = t >> 3, h = t & 7;
        unsigned short* p = Ob + (q>>3)*2304 + (192 + h*12)*8 + (q&7);
        float e[12]; float m = -1e30f;
        #pragma unroll
        for (int i=0;i<12;i++){ e[i] = b2f(p[i*8]); m = fmaxf(m, e[i]); }
        float s = 0.f;
        #pragma unroll
        for (int i=0;i<12;i++){ e[i] = __expf(e[i]-m); s += e[i]; }
        float is = 1.f/s;
        #pragma unroll
        for (int i=0;i<12;i++) p[i*8] = f2b(e[i]*is);
    }
    __syncthreads();

    // ---- 4 sub-rounds of 8 queries ----
    for (int sr = 0; sr < 4; ++sr){
        const unsigned short* raw = Ob + sr*2304;
        const int nsr = nq0 + sr*8;

        // desc: 768 sample descriptors
        for (int idx = t; idx < 768; idx += 256){
            int q = idx & 7, hp = idx >> 3;
            int lp = hp % 12;
            float fw, fh; int Wl, Hl, st;
            if (lp < 4)      { fw=160.f; fh=48.f; Wl=160; Hl=48; st=0; }
            else if (lp < 8) { fw=80.f;  fh=24.f; Wl=80;  Hl=24; st=7680; }
            else             { fw=40.f;  fh=12.f; Wl=40;  Hl=12; st=9600; }
            float offx = b2f(raw[(hp*2)*8 + q]);
            float offy = b2f(raw[(hp*2+1)*8 + q]);
            float aw   = b2f(raw[(192+hp)*8 + q]);
            float x = rp_s[(sr*8+q)*2+0]*fw - 0.5f + offx;
            float y = rp_s[(sr*8+q)*2+1]*fh - 0.5f + offy;
            float x0f = floorf(x), y0f = floorf(y);
            float lx = x-x0f, ly = y-y0f;
            int x0 = (int)x0f, y0 = (int)y0f;
            bool x0ok = (x0>=0)&&(x0<Wl), x1ok=(x0+1>=0)&&(x0+1<Wl);
            bool y0ok = (y0>=0)&&(y0<Hl), y1ok=(y0+1>=0)&&(y0+1<Hl);
            float w00 = (x0ok&&y0ok)? (1.f-lx)*(1.f-ly)*aw : 0.f;
            float w01 = (x1ok&&y0ok)? lx*(1.f-ly)*aw       : 0.f;
            float w10 = (x0ok&&y1ok)? (1.f-lx)*ly*aw       : 0.f;
            float w11 = (x1ok&&y1ok)? lx*ly*aw             : 0.f;
            int yc0 = min(max(y0,0),Hl-1), yc1 = min(max(y0+1,0),Hl-1);
            int xc0 = min(max(x0,0),Wl-1), xc1 = min(max(x0+1,0),Wl-1);
            unsigned int rb0 = (unsigned int)(st + yc0*Wl), rb1 = (unsigned int)(st + yc1*Wl);
            uint4 d;
            d.x = (rb0+(unsigned int)xc0) | ((rb0+(unsigned int)xc1)<<16);
            d.y = (rb1+(unsigned int)xc0) | ((rb1+(unsigned int)xc1)<<16);
            d.z = (unsigned int)f2b(w00) | ((unsigned int)f2b(w01)<<16);
            d.w = (unsigned int)f2b(w10) | ((unsigned int)f2b(w11)<<16);
            *(uint4*)(descB + (((unsigned int)(idx ^ ((idx>>5)&7)))<<4)) = d;
        }
        __syncthreads();

        // qv prefetch: issue residual q loads now (hidden under sampling)
        float qv[4];
        {
            const int r = t & 127, qb = t >> 7;
            #pragma unroll
            for (int qi4=0;qi4<4;qi4++)
                qv[qi4] = q_in[(size_t)(nsr + qb*4 + qi4)*CDIM + r];
        }

        // sampling: x-corner-paired mapping — 2 ch x 1 x-corner x 4 queries per thread.
        // Lanes cx=0/1 carry x0/x0+1 of the SAME sample in ONE instruction so the TA
        // merges them when they share a 64B line (50% of samples).
        {
            const int cp  = t & 7;
            const int cx  = (t >> 3) & 1;
            const int hs  = ((t >> 6) & 1)*4 + ((t >> 4) & 3);
            const int qh  = t >> 7;             // queries qh*4 .. qh*4+3
            const unsigned int vbase = (unsigned int)hs*(NVPIX*HD*2) + (unsigned int)cp*4;
            const char* vb = (const char*)value;
            float ax[4] = {0.f,0.f,0.f,0.f};
            float ay[4] = {0.f,0.f,0.f,0.f};
            #pragma unroll
            for (int lp=0; lp<12; ++lp){
                #pragma unroll
                for (int qi=0; qi<4; ++qi){
                    int q = qh*4 + qi;
                    int idx = (hs*12+lp)*8 + q;
                    uint4 d = *(const uint4*)(descB + (((unsigned int)(idx ^ ((idx>>5)&7)))<<4));
                    unsigned int p0 = cx ? (d.x >> 16) : (d.x & 0xffffu);
                    unsigned int p1 = cx ? (d.y >> 16) : (d.y & 0xffffu);
                    float wy0 = cx ? bhi(d.z) : blo(d.z);
                    float wy1 = cx ? bhi(d.w) : blo(d.w);
                    unsigned int u0 = *(const unsigned int*)(vb + vbase + (p0<<5));
                    unsigned int u1 = *(const unsigned int*)(vb + vbase + (p1<<5));
                    ax[qi] += blo(u0)*wy0 + blo(u1)*wy1;
                    ay[qi] += bhi(u0)*wy0 + bhi(u1)*wy1;
                }
            }
            #pragma unroll
            for (int qi=0;qi<4;qi++){
                ax[qi] += __shfl_xor(ax[qi], 8, 64);
                ay[qi] += __shfl_xor(ay[qi], 8, 64);
            }
            if (cx == 0){
                #pragma unroll
                for (int qi=0;qi<4;qi++){
                    int q = qh*4 + qi;
                    unsigned int pk = (unsigned int)f2b(ax[qi]) | ((unsigned int)f2b(ay[qi])<<16);
                    unsigned int bo = ((unsigned int)(q*256 + hs*32 + cp*4)) ^ (unsigned int)((q&7)<<4);
                    *(unsigned int*)(obfB + bo) = pk;
                }
            }
        }
        __syncthreads();

        // Wout projection via MFMA, bout folded
        {
            const int w = t >> 6, lane = t & 63, lr = lane & 15, lg = lane >> 4;
            f32x4 a0 = (f32x4){0.f,0.f,0.f,0.f};
            f32x4 a1 = (f32x4){0.f,0.f,0.f,0.f};
            #pragma unroll
            for (int ks=0; ks<4; ++ks){
                unsigned int bo = (unsigned int)(lr*256 + ks*64 + lg*16) ^ (unsigned int)((lr&7)<<4);
                s16x8 bfrag = *(const s16x8*)(obfB + bo);
                const unsigned short* wp = WoutBf + (size_t)(w*32 + lr)*CDIM + ks*32 + lg*8;
                s16x8 af0 = *(const s16x8*)(wp);
                s16x8 af1 = *(const s16x8*)(wp + 16*CDIM);
                a0 = __builtin_amdgcn_mfma_f32_16x16x32_bf16(af0, bfrag, a0, 0, 0, 0);
                a1 = __builtin_amdgcn_mfma_f32_16x16x32_bf16(af1, bfrag, a1, 0, 0, 0);
            }
            if (lr < 8){
                int f0 = w*32 + lg*4;
                float4 b0 = *(const float4*)(bout + f0);
                float4 b1 = *(const float4*)(bout + f0 + 16);
                float4 v0, v1;
                v0.x = a0[0]+b0.x; v0.y = a0[1]+b0.y; v0.z = a0[2]+b0.z; v0.w = a0[3]+b0.w;
                v1.x = a1[0]+b1.x; v1.y = a1[1]+b1.y; v1.z = a1[2]+b1.z; v1.w = a1[3]+b1.w;
                *(float4*)(out2 + lr*CDIM + f0)      = v0;
                *(float4*)(out2 + lr*CDIM + f0 + 16) = v1;
            }
        }
        __syncthreads();

        // residual (prefetched qv) + single-pass LN + mask + store
        {
            const int r = t & 127;
            const int qb = t >> 7;
            const int wv = t >> 6;
            float hv[4], s1[4], s2[4];
            #pragma unroll
            for (int qi4=0;qi4<4;qi4++){
                hv[qi4] = qv[qi4] + out2[(qb*4+qi4)*CDIM + r];
                s1[qi4] = hv[qi4];
                s2[qi4] = hv[qi4]*hv[qi4];
            }
            #pragma unroll
            for (int off=32; off>0; off>>=1){
                #pragma unroll
                for (int qi4=0;qi4<4;qi4++){
                    s1[qi4] += __shfl_xor(s1[qi4], off, 64);
                    s2[qi4] += __shfl_xor(s2[qi4], off, 64);
                }
            }
            if ((t&63)==0){
                #pragma unroll
                for (int qi4=0;qi4<4;qi4++){
                    wredp[0*16 + wv*4 + qi4] = s1[qi4];
                    wredp[1*16 + wv*4 + qi4] = s2[qi4];
                }
            }
            __syncthreads();

            float res[4];
            const float g = lng[r], b = lnb[r];
            #pragma unroll
            for (int qi4=0;qi4<4;qi4++){
                float mu  = (wredp[0*16 + (qb*2)*4 + qi4] + wredp[0*16 + (qb*2+1)*4 + qi4]) * (1.f/128.f);
                float msq = (wredp[1*16 + (qb*2)*4 + qi4] + wredp[1*16 + (qb*2+1)*4 + qi4]) * (1.f/128.f);
                float var = msq - mu*mu;
                float nv  = (hv[qi4]-mu) * __frsqrt_rn(var + 1e-5f) * g + b;
                res[qi4] = mask_s[sr*8 + qb*4+qi4] ? nv : qv[qi4];
            }
            float4 o; o.x=res[0]; o.y=res[1]; o.z=res[2]; o.w=res[3];
            *(float4*)(dout + (size_t)r*NQ + nsr + qb*4) = o;
        }
        __syncthreads();   // out2/desc region + wredp safe for next sub-round
    }
}

extern "C" void kernel_launch(void* const* d_in, const int* in_sizes, int n_in,
                              void* d_out, int out_size, void* d_ws, size_t ws_size,
                              hipStream_t stream){
    const float* scene  = (const float*)d_in[0];
    const float* f0     = (const float*)d_in[1];
    const float* f1     = (const float*)d_in[2];
    const float* f2     = (const float*)d_in[3];
    const float* depth  = (const float*)d_in[4];
    const float* K      = (const float*)d_in[5];
    const float* E      = (const float*)d_in[6];
    const float* vorig  = (const float*)d_in[7];
    const float* refpix = (const float*)d_in[8];
    const float* Wv     = (const float*)d_in[9];
    const float* bv     = (const float*)d_in[10];
    const float* Woff   = (const float*)d_in[11];
    const float* boff   = (const float*)d_in[12];
    const float* Wattw  = (const float*)d_in[13];
    const float* battw  = (const float*)d_in[14];
    const float* Wout   = (const float*)d_in[15];
    const float* bout   = (const float*)d_in[16];
    const float* lng    = (const float*)d_in[17];
    const float* lnb    = (const float*)d_in[18];

    char* ws = (char*)d_ws;
    // invm(512) + mask(131072) + value(2580480) + Wbf(114688) + WvT(65536)
    double*         invm   = (double*)(ws);
    unsigned char*  mask   = (unsigned char*)(ws + 512);
    unsigned short* value  = (unsigned short*)(ws + 512 + 131072);
    unsigned short* Wbf    = (unsigned short*)(ws + 512 + 131072 + 2580480);
    unsigned short* WoutBf = Wbf + 40960;
    float*          WvT    = (float*)(ws + 512 + 131072 + 2580480 + 114688);

    hipMemsetAsync(mask, 0, NQ, stream);
    inv_kernel<<<289, 256, 0, stream>>>(K, E, invm, Woff, Wattw, Wout, Wv, Wbf, WvT);

    int nVal  = NVPIX/8;            // 1260
    int nMask = (NPIX+255)/256;     // 480
    prep2_kernel<<<nVal + nMask, 256, 0, stream>>>(nVal, f0, f1, f2, WvT, bv, value,
                                                   depth, invm, vorig, mask);
    attn_fused<<<NQ/32, 256, 0, stream>>>(scene, refpix, Wbf, boff, battw, value,
                                          WoutBf, bout, lng, lnb, mask,
                                          (float*)d_out);
}

// Round 15
// 399.704 us; speedup vs baseline: 1.4875x; 1.1132x over previous
//
#include <hip/hip_runtime.h>
#include <hip/hip_bf16.h>
#include <stdint.h>

#define XS 128
#define YS 128
#define ZS 8
#define NQ (XS*YS*ZS)        // 131072 queries
#define CDIM 128
#define NH 8
#define HD 16
#define DH 192
#define DW 640
#define NPIX (DH*DW)
#define NVPIX 10080          // 7680 + 1920 + 480

typedef float f32x4 __attribute__((ext_vector_type(4)));
typedef short s16x8 __attribute__((ext_vector_type(8)));

__device__ __forceinline__ float b2f(unsigned short u){
    union { unsigned int i; float f; } v; v.i = ((unsigned int)u) << 16; return v.f;
}
__device__ __forceinline__ unsigned short f2b(float f){
    __hip_bfloat16 h = __float2bfloat16(f);
    return *reinterpret_cast<unsigned short*>(&h);
}
__device__ __forceinline__ float blo(unsigned int u){
    union { unsigned int i; float f; } v; v.i = u << 16; return v.f;
}
__device__ __forceinline__ float bhi(unsigned int u){
    union { unsigned int i; float f; } v; v.i = u & 0xffff0000u; return v.f;
}

// ------------- inverse of K/E (1 thread) + weight prep -------------
// Wbf: [0,24576) Woff | [24576,36864) Wattw | [36864,40960) zero pad | [40960,57344) Wout
// WvT (f32): WvT[ci*128+co] = Wv[co*128+ci]  (coalesced value-GEMM weights)
__global__ __launch_bounds__(256)
void inv_kernel(const float* __restrict__ K,
                const float* __restrict__ E,
                double* __restrict__ inv_out,
                const float* __restrict__ Woff,
                const float* __restrict__ Wattw,
                const float* __restrict__ Wout,
                const float* __restrict__ Wv,
                unsigned short* __restrict__ Wbf,
                float* __restrict__ WvT){
    if (blockIdx.x != 0){
        int idx = (blockIdx.x-1)*256 + threadIdx.x;
        if (idx < 24576)      Wbf[idx] = f2b(Woff[idx]);
        else if (idx < 36864) Wbf[idx] = f2b(Wattw[idx-24576]);
        else if (idx < 40960) Wbf[idx] = 0;
        else if (idx < 57344) Wbf[idx] = f2b(Wout[idx-40960]);
        else if (idx < 73728){
            int j = idx - 57344;
            int ci = j >> 7, co = j & 127;
            WvT[j] = Wv[co*128 + ci];
        }
        return;
    }
    if (threadIdx.x != 0) return;
    double k[3][3], e[4][4];
    for (int i=0;i<9;i++)  k[i/3][i%3] = (double)K[i];
    for (int i=0;i<16;i++) e[i/4][i%4] = (double)E[i];
    double det = k[0][0]*(k[1][1]*k[2][2]-k[1][2]*k[2][1])
               - k[0][1]*(k[1][0]*k[2][2]-k[1][2]*k[2][0])
               + k[0][2]*(k[1][0]*k[2][1]-k[1][1]*k[2][0]);
    double id = 1.0/det;
    double inv[3][3];
    inv[0][0]=(k[1][1]*k[2][2]-k[1][2]*k[2][1])*id;
    inv[0][1]=(k[0][2]*k[2][1]-k[0][1]*k[2][2])*id;
    inv[0][2]=(k[0][1]*k[1][2]-k[0][2]*k[1][1])*id;
    inv[1][0]=(k[1][2]*k[2][0]-k[1][0]*k[2][2])*id;
    inv[1][1]=(k[0][0]*k[2][2]-k[0][2]*k[2][0])*id;
    inv[1][2]=(k[0][2]*k[1][0]-k[0][0]*k[1][2])*id;
    inv[2][0]=(k[1][0]*k[2][1]-k[1][1]*k[2][0])*id;
    inv[2][1]=(k[0][1]*k[2][0]-k[0][0]*k[2][1])*id;
    inv[2][2]=(k[0][0]*k[1][1]-k[0][1]*k[1][0])*id;
    for (int i=0;i<9;i++) inv_out[i] = inv[i/3][i%3];
    double a[4][8];
    for (int i=0;i<4;i++){ for(int j=0;j<4;j++){ a[i][j]=e[i][j]; a[i][4+j]=(i==j)?1.0:0.0; } }
    for (int c=0;c<4;c++){
        int piv=c; double best=fabs(a[c][c]);
        for (int r=c+1;r<4;r++){ double v=fabs(a[r][c]); if (v>best){best=v;piv=r;} }
        if (piv!=c){ for (int j=0;j<8;j++){ double tmp=a[c][j]; a[c][j]=a[piv][j]; a[piv][j]=tmp; } }
        double pv = 1.0/a[c][c];
        for (int j=0;j<8;j++) a[c][j]*=pv;
        for (int r=0;r<4;r++){
            if (r==c) continue;
            double f=a[r][c];
            for(int j=0;j<8;j++) a[r][j]-=f*a[c][j];
        }
    }
    for (int i=0;i<16;i++) inv_out[9+i] = a[i/4][4 + (i%4)];
}

// ================= prep2: value GEMM (WvT-coalesced) | mask =================
__global__ __launch_bounds__(256)
void prep2_kernel(int nVal,
                  const float* __restrict__ f0,
                  const float* __restrict__ f1,
                  const float* __restrict__ f2,
                  const float* __restrict__ WvT,   // [128 ci][128 co] f32
                  const float* __restrict__ bv,
                  unsigned short* __restrict__ value,  // [NH][NVPIX][HD]
                  const float* __restrict__ depth,
                  const double* __restrict__ invm,
                  const float* __restrict__ vorigin,
                  unsigned char* __restrict__ mask){
    __shared__ float fl[128][8];     // [ci][pix]
    const int t = threadIdx.x;
    if ((int)blockIdx.x < nVal){
        // ---------- value: 8 pixels/block; thread = (pix, co-quad) ----------
        const int p0 = blockIdx.x*8;
        const float* src; int hw, lp;
        if (p0 < 7680)      { src=f0; hw=7680; lp=p0; }
        else if (p0 < 9600) { src=f1; hw=1920; lp=p0-7680; }
        else                { src=f2; hw=480;  lp=p0-9600; }
        // stage: thread t loads float4 of channel t>>1, pixels (t&1)*4..+3
        {
            int ch = t >> 1, po = (t & 1)*4;
            float4 v = *(const float4*)(src + (size_t)ch*hw + lp + po);
            fl[ch][po+0]=v.x; fl[ch][po+1]=v.y; fl[ch][po+2]=v.z; fl[ch][po+3]=v.w;
        }
        __syncthreads();
        const int pix = t >> 5, cq = t & 31;      // co = cq*4 .. cq*4+3
        float4 bvv = *(const float4*)(bv + cq*4);
        float acc0=bvv.x, acc1=bvv.y, acc2=bvv.z, acc3=bvv.w;
        const float4* wvt = (const float4*)WvT + cq;   // row ci: wvt[ci*32]
        #pragma unroll 4
        for (int ci=0; ci<128; ++ci){
            float4 w4 = wvt[ci*32];               // coalesced 512B/wave
            float fv = fl[ci][pix];               // broadcast
            acc0 += w4.x*fv; acc1 += w4.y*fv; acc2 += w4.z*fv; acc3 += w4.w*fv;
        }
        const int h = cq >> 2, cc0 = (cq & 3)*4;
        unsigned short* vp = value + ((size_t)h*NVPIX + (size_t)(p0+pix))*HD + cc0;
        ushort4 o; o.x=f2b(acc0); o.y=f2b(acc1); o.z=f2b(acc2); o.w=f2b(acc3);
        *(ushort4*)vp = o;
    } else {
        int tid = (blockIdx.x - nVal)*256 + t;
        if (tid >= NPIX) return;
        int gx = tid % DW, gy = tid / DW;
        double d  = (double)depth[tid];
        double X0 = (double)gx * d, X1 = (double)gy * d, X2 = d;
        double c0 = invm[0]*X0 + invm[1]*X1 + invm[2]*X2;
        double c1 = invm[3]*X0 + invm[4]*X1 + invm[5]*X2;
        double c2 = invm[6]*X0 + invm[7]*X1 + invm[8]*X2;
        const double* iE = invm + 9;
        double w0 = iE[0]*c0 + iE[1]*c1 + iE[2]*c2  + iE[3];
        double w1 = iE[4]*c0 + iE[5]*c1 + iE[6]*c2  + iE[7];
        double w2 = iE[8]*c0 + iE[9]*c1 + iE[10]*c2 + iE[11];
        double v0 = (w0-(double)vorigin[0])/0.4 - 0.5;
        double v1 = (w1-(double)vorigin[1])/0.4 - 0.5;
        double v2 = ((w2-(double)vorigin[2])/0.4 - 0.5) / 2.0;
        int xi = (int)v0, yi = (int)v1, zi = (int)v2;
        if (xi>=0 && xi<XS && yi>=0 && yi<YS && zi>=0 && zi<ZS)
            mask[(xi*YS + yi)*ZS + zi] = 1;
    }
}

// ======== attn_fused32: offaw MFMA + softmax + 4x{desc, qv-prefetch, sampling, Wout, LN} ========
__global__ __launch_bounds__(256, 2)
void attn_fused(const float* __restrict__ q_in,
                const float* __restrict__ refpix,
                const unsigned short* __restrict__ Wbf,    // [320][128] bf16 (padded)
                const float* __restrict__ boff,
                const float* __restrict__ battw,
                const unsigned short* __restrict__ value,  // [NH][NVPIX][HD]
                const unsigned short* __restrict__ WoutBf, // [128][128] bf16
                const float* __restrict__ bout,
                const float* __restrict__ lng,
                const float* __restrict__ lnb,
                const unsigned char* __restrict__ mask,
                float* __restrict__ dout){
    const int nq0 = blockIdx.x * 32;
    const int t = threadIdx.x;
    __shared__ __align__(16) unsigned char smem[36384];
    unsigned short* Ob    = (unsigned short*)smem;
    unsigned char*  qbfB  = smem + 18432;
    unsigned char*  descB = smem + 18432;
    float*          out2  = (float*)(smem + 18432);
    unsigned char*  obfB  = smem + 30720;
    float*          bias  = (float*)(smem + 34816);
    float*          rp_s  = (float*)(smem + 35968);
    unsigned char*  mask_s= smem + 36224;
    float*          wredp = (float*)(smem + 36256);

    // ---- stage: q -> swizzled bf16, bias, rp, mask, zero obf pad rows ----
    #pragma unroll
    for (int i=0;i<4;i++){
        int idx = t + i*256;              // 1024 float4s = 32 rows x 32
        int row = idx >> 5, c4 = idx & 31;
        float4 qv = ((const float4*)(q_in + (size_t)(nq0+row)*CDIM))[c4];
        unsigned int pk0 = (unsigned int)f2b(qv.x) | ((unsigned int)f2b(qv.y)<<16);
        unsigned int pk1 = (unsigned int)f2b(qv.z) | ((unsigned int)f2b(qv.w)<<16);
        unsigned int bo = ((unsigned int)(row*256 + c4*8)) ^ (unsigned int)((row&7)<<4);
        *(unsigned int*)(qbfB + bo)     = pk0;
        *(unsigned int*)(qbfB + bo + 4) = pk1;
    }
    for (int i=t;i<288;i+=256) bias[i] = (i<192)? boff[i] : battw[i-192];
    ((unsigned int*)obfB)[512 + t] = 0;   // zero obf rows 8..15
    ((unsigned int*)obfB)[768 + t] = 0;
    if (t < 64) rp_s[t] = refpix[nq0*2 + t];
    if (t < 32) mask_s[t] = mask[nq0 + t];
    __syncthreads();

    // ---- offaw MFMA: 5 feature tiles x 2 query tiles x 4 K-steps per wave ----
    {
        const int w = t >> 6, lane = t & 63, lr = lane & 15, lg = lane >> 4;
        const int nt0 = w*5;
        f32x4 acc[5][2];
        #pragma unroll
        for (int j=0;j<5;j++){ acc[j][0]=(f32x4){0,0,0,0}; acc[j][1]=(f32x4){0,0,0,0}; }
        #pragma unroll
        for (int ks=0; ks<4; ++ks){
            s16x8 bf[2];
            #pragma unroll
            for (int qt=0;qt<2;qt++){
                int qrow = qt*16 + lr;
                unsigned int bo = ((unsigned int)(qrow*256 + ks*64 + lg*16)) ^ (unsigned int)((qrow&7)<<4);
                bf[qt] = *(const s16x8*)(qbfB + bo);
            }
            const unsigned short* wp = Wbf + (size_t)(nt0*16 + lr)*CDIM + ks*32 + lg*8;
            #pragma unroll
            for (int j=0;j<5;++j){
                s16x8 af = *(const s16x8*)(wp + j*16*CDIM);
                acc[j][0] = __builtin_amdgcn_mfma_f32_16x16x32_bf16(af, bf[0], acc[j][0], 0, 0, 0);
                acc[j][1] = __builtin_amdgcn_mfma_f32_16x16x32_bf16(af, bf[1], acc[j][1], 0, 0, 0);
            }
        }
        #pragma unroll
        for (int j=0;j<5;++j){
            int nt = nt0 + j;
            if (nt < 18){
                #pragma unroll
                for (int qt=0;qt<2;qt++){
                    int q = qt*16 + lr;
                    int base = (q>>3)*2304 + (q&7);
                    #pragma unroll
                    for (int r=0;r<4;++r){
                        int f = nt*16 + lg*4 + r;
                        Ob[base + f*8] = f2b(acc[j][qt][r] + bias[f]);
                    }
                }
            }
        }
    }
    __syncthreads();

    // ---- softmax: 32q x 8h = 256 tasks, one per thread ----
    {
        int q = t >> 3, h = t & 7;
        unsigned short* p = Ob + (q>>3)*2304 + (192 + h*12)*8 + (q&7);
        float e[12]; float m = -1e30f;
        #pragma unroll
        for (int i=0;i<12;i++){ e[i] = b2f(p[i*8]); m = fmaxf(m, e[i]); }
        float s = 0.f;
        #pragma unroll
        for (int i=0;i<12;i++){ e[i] = __expf(e[i]-m); s += e[i]; }
        float is = 1.f/s;
        #pragma unroll
        for (int i=0;i<12;i++) p[i*8] = f2b(e[i]*is);
    }
    __syncthreads();

    // ---- 4 sub-rounds of 8 queries ----
    for (int sr = 0; sr < 4; ++sr){
        const unsigned short* raw = Ob + sr*2304;
        const int nsr = nq0 + sr*8;

        // desc: 768 sample descriptors
        for (int idx = t; idx < 768; idx += 256){
            int q = idx & 7, hp = idx >> 3;
            int lp = hp % 12;
            float fw, fh; int Wl, Hl, st;
            if (lp < 4)      { fw=160.f; fh=48.f; Wl=160; Hl=48; st=0; }
            else if (lp < 8) { fw=80.f;  fh=24.f; Wl=80;  Hl=24; st=7680; }
            else             { fw=40.f;  fh=12.f; Wl=40;  Hl=12; st=9600; }
            float offx = b2f(raw[(hp*2)*8 + q]);
            float offy = b2f(raw[(hp*2+1)*8 + q]);
            float aw   = b2f(raw[(192+hp)*8 + q]);
            float x = rp_s[(sr*8+q)*2+0]*fw - 0.5f + offx;
            float y = rp_s[(sr*8+q)*2+1]*fh - 0.5f + offy;
            float x0f = floorf(x), y0f = floorf(y);
            float lx = x-x0f, ly = y-y0f;
            int x0 = (int)x0f, y0 = (int)y0f;
            bool x0ok = (x0>=0)&&(x0<Wl), x1ok=(x0+1>=0)&&(x0+1<Wl);
            bool y0ok = (y0>=0)&&(y0<Hl), y1ok=(y0+1>=0)&&(y0+1<Hl);
            float w00 = (x0ok&&y0ok)? (1.f-lx)*(1.f-ly)*aw : 0.f;
            float w01 = (x1ok&&y0ok)? lx*(1.f-ly)*aw       : 0.f;
            float w10 = (x0ok&&y1ok)? (1.f-lx)*ly*aw       : 0.f;
            float w11 = (x1ok&&y1ok)? lx*ly*aw             : 0.f;
            int yc0 = min(max(y0,0),Hl-1), yc1 = min(max(y0+1,0),Hl-1);
            int xc0 = min(max(x0,0),Wl-1), xc1 = min(max(x0+1,0),Wl-1);
            unsigned int rb0 = (unsigned int)(st + yc0*Wl), rb1 = (unsigned int)(st + yc1*Wl);
            uint4 d;
            d.x = (rb0+(unsigned int)xc0) | ((rb0+(unsigned int)xc1)<<16);
            d.y = (rb1+(unsigned int)xc0) | ((rb1+(unsigned int)xc1)<<16);
            d.z = (unsigned int)f2b(w00) | ((unsigned int)f2b(w01)<<16);
            d.w = (unsigned int)f2b(w10) | ((unsigned int)f2b(w11)<<16);
            *(uint4*)(descB + (((unsigned int)(idx ^ ((idx>>5)&7)))<<4)) = d;
        }
        __syncthreads();

        // qv prefetch: issue residual q loads now (hidden under sampling)
        float qv[4];
        {
            const int r = t & 127, qb = t >> 7;
            #pragma unroll
            for (int qi4=0;qi4<4;qi4++)
                qv[qi4] = q_in[(size_t)(nsr + qb*4 + qi4)*CDIM + r];
        }

        // sampling: 2 channels x 2 queries per thread, u32-offset gathers
        {
            const int cp = t & 7, hs = (t>>3) & 7, qgs = t >> 6;
            const unsigned int vbase = (unsigned int)hs*(NVPIX*HD*2) + (unsigned int)cp*4;
            const char* vb = (const char*)value;
            float av0x=0.f, av0y=0.f, av1x=0.f, av1y=0.f;
            #pragma unroll
            for (int lp=0; lp<12; ++lp){
                #pragma unroll
                for (int qi2=0; qi2<2; ++qi2){
                    int idx = (hs*12+lp)*8 + qgs*2 + qi2;
                    uint4 d = *(const uint4*)(descB + (((unsigned int)(idx ^ ((idx>>5)&7)))<<4));
                    unsigned int o00 = vbase + ((d.x & 0xffffu)<<5);
                    unsigned int o01 = vbase + ((d.x >> 16)<<5);
                    unsigned int o10 = vbase + ((d.y & 0xffffu)<<5);
                    unsigned int o11 = vbase + ((d.y >> 16)<<5);
                    unsigned int u00 = *(const unsigned int*)(vb + o00);
                    unsigned int u01 = *(const unsigned int*)(vb + o01);
                    unsigned int u10 = *(const unsigned int*)(vb + o10);
                    unsigned int u11 = *(const unsigned int*)(vb + o11);
                    float w00 = blo(d.z), w01 = bhi(d.z), w10 = blo(d.w), w11 = bhi(d.w);
                    float sx = blo(u00)*w00 + blo(u01)*w01 + blo(u10)*w10 + blo(u11)*w11;
                    float sy = bhi(u00)*w00 + bhi(u01)*w01 + bhi(u10)*w10 + bhi(u11)*w11;
                    if (qi2 == 0){ av0x += sx; av0y += sy; }
                    else         { av1x += sx; av1y += sy; }
                }
            }
            const int q0q = qgs*2;
            unsigned int pk0 = (unsigned int)f2b(av0x) | ((unsigned int)f2b(av0y)<<16);
            unsigned int pk1 = (unsigned int)f2b(av1x) | ((unsigned int)f2b(av1y)<<16);
            unsigned int bo0 = (unsigned int)(q0q*256 + hs*32 + cp*4)     ^ (unsigned int)((q0q&7)<<4);
            unsigned int bo1 = (unsigned int)((q0q+1)*256 + hs*32 + cp*4) ^ (unsigned int)(((q0q+1)&7)<<4);
            *(unsigned int*)(obfB + bo0) = pk0;
            *(unsigned int*)(obfB + bo1) = pk1;
        }
        __syncthreads();

        // Wout projection via MFMA, bout folded
        {
            const int w = t >> 6, lane = t & 63, lr = lane & 15, lg = lane >> 4;
            f32x4 a0 = (f32x4){0.f,0.f,0.f,0.f};
            f32x4 a1 = (f32x4){0.f,0.f,0.f,0.f};
            #pragma unroll
            for (int ks=0; ks<4; ++ks){
                unsigned int bo = (unsigned int)(lr*256 + ks*64 + lg*16) ^ (unsigned int)((lr&7)<<4);
                s16x8 bfrag = *(const s16x8*)(obfB + bo);
                const unsigned short* wp = WoutBf + (size_t)(w*32 + lr)*CDIM + ks*32 + lg*8;
                s16x8 af0 = *(const s16x8*)(wp);
                s16x8 af1 = *(const s16x8*)(wp + 16*CDIM);
                a0 = __builtin_amdgcn_mfma_f32_16x16x32_bf16(af0, bfrag, a0, 0, 0, 0);
                a1 = __builtin_amdgcn_mfma_f32_16x16x32_bf16(af1, bfrag, a1, 0, 0, 0);
            }
            if (lr < 8){
                int f0 = w*32 + lg*4;
                float4 b0 = *(const float4*)(bout + f0);
                float4 b1 = *(const float4*)(bout + f0 + 16);
                float4 v0, v1;
                v0.x = a0[0]+b0.x; v0.y = a0[1]+b0.y; v0.z = a0[2]+b0.z; v0.w = a0[3]+b0.w;
                v1.x = a1[0]+b1.x; v1.y = a1[1]+b1.y; v1.z = a1[2]+b1.z; v1.w = a1[3]+b1.w;
                *(float4*)(out2 + lr*CDIM + f0)      = v0;
                *(float4*)(out2 + lr*CDIM + f0 + 16) = v1;
            }
        }
        __syncthreads();

        // residual (prefetched qv) + single-pass LN + mask + store
        {
            const int r = t & 127;
            const int qb = t >> 7;
            const int wv = t >> 6;
            float hv[4], s1[4], s2[4];
            #pragma unroll
            for (int qi4=0;qi4<4;qi4++){
                hv[qi4] = qv[qi4] + out2[(qb*4+qi4)*CDIM + r];
                s1[qi4] = hv[qi4];
                s2[qi4] = hv[qi4]*hv[qi4];
            }
            #pragma unroll
            for (int off=32; off>0; off>>=1){
                #pragma unroll
                for (int qi4=0;qi4<4;qi4++){
                    s1[qi4] += __shfl_xor(s1[qi4], off, 64);
                    s2[qi4] += __shfl_xor(s2[qi4], off, 64);
                }
            }
            if ((t&63)==0){
                #pragma unroll
                for (int qi4=0;qi4<4;qi4++){
                    wredp[0*16 + wv*4 + qi4] = s1[qi4];
                    wredp[1*16 + wv*4 + qi4] = s2[qi4];
                }
            }
            __syncthreads();

            float res[4];
            const float g = lng[r], b = lnb[r];
            #pragma unroll
            for (int qi4=0;qi4<4;qi4++){
                float mu  = (wredp[0*16 + (qb*2)*4 + qi4] + wredp[0*16 + (qb*2+1)*4 + qi4]) * (1.f/128.f);
                float msq = (wredp[1*16 + (qb*2)*4 + qi4] + wredp[1*16 + (qb*2+1)*4 + qi4]) * (1.f/128.f);
                float var = msq - mu*mu;
                float nv  = (hv[qi4]-mu) * __frsqrt_rn(var + 1e-5f) * g + b;
                res[qi4] = mask_s[sr*8 + qb*4+qi4] ? nv : qv[qi4];
            }
            float4 o; o.x=res[0]; o.y=res[1]; o.z=res[2]; o.w=res[3];
            *(float4*)(dout + (size_t)r*NQ + nsr + qb*4) = o;
        }
        __syncthreads();   // out2/desc region + wredp safe for next sub-round
    }
}

extern "C" void kernel_launch(void* const* d_in, const int* in_sizes, int n_in,
                              void* d_out, int out_size, void* d_ws, size_t ws_size,
                              hipStream_t stream){
    const float* scene  = (const float*)d_in[0];
    const float* f0     = (const float*)d_in[1];
    const float* f1     = (const float*)d_in[2];
    const float* f2     = (const float*)d_in[3];
    const float* depth  = (const float*)d_in[4];
    const float* K      = (const float*)d_in[5];
    const float* E      = (const float*)d_in[6];
    const float* vorig  = (const float*)d_in[7];
    const float* refpix = (const float*)d_in[8];
    const float* Wv     = (const float*)d_in[9];
    const float* bv     = (const float*)d_in[10];
    const float* Woff   = (const float*)d_in[11];
    const float* boff   = (const float*)d_in[12];
    const float* Wattw  = (const float*)d_in[13];
    const float* battw  = (const float*)d_in[14];
    const float* Wout   = (const float*)d_in[15];
    const float* bout   = (const float*)d_in[16];
    const float* lng    = (const float*)d_in[17];
    const float* lnb    = (const float*)d_in[18];

    char* ws = (char*)d_ws;
    // invm(512) + mask(131072) + value(2580480) + Wbf(114688) + WvT(65536)
    double*         invm   = (double*)(ws);
    unsigned char*  mask   = (unsigned char*)(ws + 512);
    unsigned short* value  = (unsigned short*)(ws + 512 + 131072);
    unsigned short* Wbf    = (unsigned short*)(ws + 512 + 131072 + 2580480);
    unsigned short* WoutBf = Wbf + 40960;
    float*          WvT    = (float*)(ws + 512 + 131072 + 2580480 + 114688);

    hipMemsetAsync(mask, 0, NQ, stream);
    inv_kernel<<<289, 256, 0, stream>>>(K, E, invm, Woff, Wattw, Wout, Wv, Wbf, WvT);

    int nVal  = NVPIX/8;            // 1260
    int nMask = (NPIX+255)/256;     // 480
    prep2_kernel<<<nVal + nMask, 256, 0, stream>>>(nVal, f0, f1, f2, WvT, bv, value,
                                                   depth, invm, vorig, mask);
    attn_fused<<<NQ/32, 256, 0, stream>>>(scene, refpix, Wbf, boff, battw, value,
                                          WoutBf, bout, lng, lnb, mask,
                                          (float*)d_out);
}